// Round 6
// baseline (614.845 us; speedup 1.0000x reference)
//
#include <hip/hip_runtime.h>

#define NMAT 1000
#define SA_PAD 68        // fp32 LDS row stride (16B-aligned rows, 2-way max bank conflict)

// ws layout (bytes):
//   [8,192,000, 8,355,840)  seedF: fp32[10][64][64]   (M^(2^k), k=0..9)
//   [8,355,840, 8,486,912)  x0b  : bf16[1024][64]     (x0 slice, bf16)
// (first 8 MB unused now that the per-t table is fused away; offsets kept stable)
#define SEEDF_OFF 2048000          // float offset of seedF
#define X0B_OFF   8355840          // byte offset of x0b

typedef short short8 __attribute__((ext_vector_type(8)));    // 8 x bf16 payload for MFMA operands
typedef float floatx4 __attribute__((ext_vector_type(4)));   // MFMA accumulator
typedef unsigned short ushortx4 __attribute__((ext_vector_type(4)));

__device__ __forceinline__ unsigned short f2bf(float f) {
    // fp32 -> bf16 round-to-nearest-even
    unsigned int u = __float_as_uint(f);
    u += 0x7fffu + ((u >> 16) & 1u);
    return (unsigned short)(u >> 16);
}

__device__ __forceinline__ short8 pack_bf8(float4 a, float4 b) {
    short8 r;
    r[0] = (short)f2bf(a.x); r[1] = (short)f2bf(a.y);
    r[2] = (short)f2bf(a.z); r[3] = (short)f2bf(a.w);
    r[4] = (short)f2bf(b.x); r[5] = (short)f2bf(b.y);
    r[6] = (short)f2bf(b.z); r[7] = (short)f2bf(b.w);
    return r;
}

// 64x64x64 fp32 MAC core over LDS operands (row stride SA_PAD).
// 256 threads; each accumulates a 4x4 tile at (r0, c0).
__device__ __forceinline__ void mm_core(const float* __restrict__ sA,
                                        const float* __restrict__ sB,
                                        int r0, int c0, float acc[4][4])
{
#pragma unroll
    for (int k = 0; k < 64; k += 4) {
        float4 b0 = *(const float4*)&sB[(k + 0) * SA_PAD + c0];
        float4 b1 = *(const float4*)&sB[(k + 1) * SA_PAD + c0];
        float4 b2 = *(const float4*)&sB[(k + 2) * SA_PAD + c0];
        float4 b3 = *(const float4*)&sB[(k + 3) * SA_PAD + c0];
#pragma unroll
        for (int u = 0; u < 4; ++u) {
            float4 a = *(const float4*)&sA[(r0 + u) * SA_PAD + k];
            acc[u][0] += a.x * b0.x + a.y * b1.x + a.z * b2.x + a.w * b3.x;
            acc[u][1] += a.x * b0.y + a.y * b1.y + a.z * b2.y + a.w * b3.y;
            acc[u][2] += a.x * b0.z + a.y * b1.z + a.z * b2.z + a.w * b3.z;
            acc[u][3] += a.x * b0.w + a.y * b1.w + a.z * b2.w + a.w * b3.w;
        }
    }
}

// Vectorized global(64x64 fp32, stride 64) -> LDS(stride SA_PAD) copy; 4 float4 per thread.
__device__ __forceinline__ void stageLDS(float* __restrict__ s, const float* __restrict__ g, int tid)
{
#pragma unroll
    for (int q = 0; q < 4; ++q) {
        int i4 = tid + 256 * q;                 // 0..1023 float4 chunks
        int r = i4 >> 4, c4 = (i4 & 15) * 4;
        *(float4*)&s[r * SA_PAD + c4] = *(const float4*)&g[i4 * 4];
    }
}

// Kernel 1: block 0 computes M = expm(K) (degree-12 Taylor, Paterson-Stockmeyer) all-LDS,
// then seeds M^(2^k), k=0..9 -> seedF (fp32). Blocks 1..16 convert x0 to bf16 concurrently.
__global__ __launch_bounds__(256) void k_build(const float* __restrict__ K,
                                               const float* __restrict__ in,
                                               float* __restrict__ ws)
{
    const int tid = threadIdx.x;
    unsigned short* x0b = (unsigned short*)((char*)ws + X0B_OFF);

    if (blockIdx.x != 0) {
        // x0 bf16 conversion: 64 batch-rows per block
        const int rb = (blockIdx.x - 1) * 64;
#pragma unroll
        for (int q = 0; q < 4; ++q) {
            int i4 = tid + 256 * q;             // 1024 float4 chunks of 4096 floats
            int b = rb + (i4 >> 4), c4 = (i4 & 15) * 4;
            float4 v = *(const float4*)&in[(size_t)b * 64000 + c4];   // t=0 slice
            ushortx4 h = { f2bf(v.x), f2bf(v.y), f2bf(v.z), f2bf(v.w) };
            *(ushortx4*)&x0b[(size_t)b * 64 + c4] = h;
        }
        return;
    }

    // ---- block 0: expm chain ----
    __shared__ __align__(16) float smem[6 * 64 * SA_PAD];   // 104,448 B

    // load K -> buf0
#pragma unroll
    for (int q = 0; q < 4; ++q) {
        int i4 = tid + 256 * q;
        int r = i4 >> 4, c4 = (i4 & 15) * 4;
        *(float4*)&smem[r * SA_PAD + c4] = *(const float4*)&K[i4 * 4];
    }

    const float c1_ = 1.f, c2_ = 0.5f, c3_ = 1.f / 6.f, c4_ = 1.f / 24.f, c5_ = 1.f / 120.f,
                c6_ = 1.f / 720.f, c7_ = 1.f / 5040.f, c8_ = 1.f / 40320.f, c9_ = 1.f / 362880.f,
                c10_ = 1.f / 3628800.f, c11_ = 1.f / 39916800.f, c12_ = 1.f / 479001600.f;

    // bufs: 0:K->M4->M256  1:T2->M8->M512  2:T3->M16  3:T4->M32  4:P1->M->M64  5:P2->M2->M128
    // ops : T2  T3  T4  P2  M   M2  M4  M8  M16 M32 M64 M128 M256 M512
    const signed char SD[14]  = {1, 2, 3, 5, 4, 5, 0, 1, 2, 3, 4, 5, 0, 1};
    const signed char SAi[14] = {0, 1, 1, 4, 5, 4, 5, 0, 1, 2, 3, 4, 5, 0};
    const signed char SBi[14] = {0, 0, 1, 3, 3, 4, 5, 0, 1, 2, 3, 4, 5, 0};
    const signed char SE[14]  = {-1, -1, -1, 0, 1, -1, -1, -1, -1, -1, -1, -1, -1, -1};
    const signed char SSd[14] = {-1, -1, -1, -1, 0, 1, 2, 3, 4, 5, 6, 7, 8, 9};  // seedF slot

    const int r0 = (tid >> 4) * 4, c0 = (tid & 15) * 4;

#pragma unroll 1
    for (int st = 0; st < 14; ++st) {
        if (st == 3) {
            // P1 = c12*T4 + c8*I + c9*K + c10*T2 + c11*T3  -> buf4
            __syncthreads();
#pragma unroll
            for (int s = 0; s < 16; ++s) {
                int idx = tid + 256 * s;
                int r = idx >> 6, c = idx & 63;
                smem[4 * (64 * SA_PAD) + r * SA_PAD + c] =
                      c12_ * smem[3 * (64 * SA_PAD) + r * SA_PAD + c] + (r == c ? c8_ : 0.f)
                    + c9_  * smem[0 * (64 * SA_PAD) + r * SA_PAD + c]
                    + c10_ * smem[1 * (64 * SA_PAD) + r * SA_PAD + c]
                    + c11_ * smem[2 * (64 * SA_PAD) + r * SA_PAD + c];
            }
        }
        __syncthreads();   // prev-step writes visible; prev-step reads complete
        const float* A = smem + (int)SAi[st] * (64 * SA_PAD);
        const float* B = smem + (int)SBi[st] * (64 * SA_PAD);
        float acc[4][4] = {};
        mm_core(A, B, r0, c0, acc);

        float cI = 0.f, cK = 0.f, cT2 = 0.f, cT3 = 0.f;
        const int epi = SE[st];
        if (epi == 0) { cI = c4_; cK = c5_; cT2 = c6_; cT3 = c7_; }
        if (epi == 1) { cI = 1.f; cK = c1_; cT2 = c2_; cT3 = c3_; }

        float* D = smem + (int)SD[st] * (64 * SA_PAD);
        float* sf = (SSd[st] >= 0) ? (ws + SEEDF_OFF + (size_t)SSd[st] * 4096) : nullptr;
#pragma unroll
        for (int u = 0; u < 4; ++u) {
            int r = r0 + u;
            float o[4];
#pragma unroll
            for (int v = 0; v < 4; ++v) {
                int c = c0 + v;
                float val = acc[u][v];
                if (epi >= 0) {
                    val += (r == c ? cI : 0.f)
                         + cK  * smem[0 * (64 * SA_PAD) + r * SA_PAD + c]
                         + cT2 * smem[1 * (64 * SA_PAD) + r * SA_PAD + c]
                         + cT3 * smem[2 * (64 * SA_PAD) + r * SA_PAD + c];
                }
                o[v] = val;
            }
            float4 vv = {o[0], o[1], o[2], o[3]};
            *(float4*)&D[r * SA_PAD + c0] = vv;
            if (sf) *(float4*)&sf[r * 64 + c0] = vv;
        }
    }
}

// Kernel 2 (fused): block t builds M^t (fp32 chain over seeds, MSB-first — bit-identical to
// the old k_pows) in LDS, extracts bf16 MFMA A-fragments from it, then streams
// y[b, t, :] for ALL 1024 batch rows barrier-free with swapped-operand MFMA + float4 stores.
// 2-buffer chain (34.8 KB LDS) -> 4 blocks/CU -> all 1000 blocks co-resident.
__global__ __launch_bounds__(256) void k_fused(const float* __restrict__ ws,
                                               float* __restrict__ out)
{
    __shared__ __align__(16) float P[64 * SA_PAD];    // running product / final M^t
    __shared__ __align__(16) float Bs[64 * SA_PAD];   // current seed operand

    const int t = blockIdx.x;
    const int tid = threadIdx.x;
    const unsigned short* x0b = (const unsigned short*)((const char*)ws + X0B_OFF);

    if (t == 0) {
        // y[:,0,:] = fp32(bf16(x0))  (== MFMA(I, x0) exactly)
#pragma unroll 1
        for (int q = 0; q < 64; ++q) {
            int i4 = tid + 256 * q;             // 16384 float4 chunks of 65536 floats
            int b = i4 >> 4, c4 = (i4 & 15) * 4;
            ushortx4 h = *(const ushortx4*)&x0b[(size_t)b * 64 + c4];
            float4 v;
            v.x = __uint_as_float((unsigned)(unsigned short)h[0] << 16);
            v.y = __uint_as_float((unsigned)(unsigned short)h[1] << 16);
            v.z = __uint_as_float((unsigned)(unsigned short)h[2] << 16);
            v.w = __uint_as_float((unsigned)(unsigned short)h[3] << 16);
            *(float4*)&out[(size_t)b * 64000 + c4] = v;
        }
        return;
    }

    const float* seedF = ws + SEEDF_OFF;
    const int r0 = (tid >> 4) * 4, c0 = (tid & 15) * 4;

    // ---- chain phase: P = product of seeds over set bits of t, MSB-first ----
    int hb = 31 - __clz(t);
    stageLDS(P, seedF + (size_t)hb * 4096, tid);
    int rem = t & ~(1 << hb);

    if (rem) {
        float4 rg[4];
        {
            int b = 31 - __clz(rem); rem &= ~(1 << b);
            const float* g = seedF + (size_t)b * 4096;
#pragma unroll
            for (int q = 0; q < 4; ++q) rg[q] = *(const float4*)&g[(tid + 256 * q) * 4];
        }
        while (true) {
            __syncthreads();            // P staged/written
            // commit prefetched seed to Bs
#pragma unroll
            for (int q = 0; q < 4; ++q) {
                int i4 = tid + 256 * q;
                int rr = i4 >> 4, c4 = (i4 & 15) * 4;
                *(float4*)&Bs[rr * SA_PAD + c4] = rg[q];
            }
            // prefetch next seed (overlaps the matmul)
            int nb = -1;
            if (rem) {
                nb = 31 - __clz(rem); rem &= ~(1 << nb);
                const float* g = seedF + (size_t)nb * 4096;
#pragma unroll
                for (int q = 0; q < 4; ++q) rg[q] = *(const float4*)&g[(tid + 256 * q) * 4];
            }
            __syncthreads();            // Bs visible
            float acc[4][4] = {};
            mm_core(P, Bs, r0, c0, acc);
            __syncthreads();            // all reads of P done
#pragma unroll
            for (int u = 0; u < 4; ++u) {
                float4 vv = {acc[u][0], acc[u][1], acc[u][2], acc[u][3]};
                *(float4*)&P[(r0 + u) * SA_PAD + c0] = vv;
            }
            if (nb < 0) break;
        }
    }
    __syncthreads();                    // final P visible to all waves

    // ---- fragment extraction: bf16 A-fragments straight from fp32 P ----
    const int lane = tid & 63;
    const int w = tid >> 6;             // wave 0..3
    const int m = lane & 15;            // fragment index within 16
    const int kg = lane >> 4;           // k-octet group 0..3

    short8 ma[4][2];
#pragma unroll
    for (int n = 0; n < 4; ++n) {
        const float* row = &P[(n * 16 + m) * SA_PAD];
        float4 f0 = *(const float4*)&row[kg * 8];
        float4 f1 = *(const float4*)&row[kg * 8 + 4];
        ma[n][0] = pack_bf8(f0, f1);
        float4 g0 = *(const float4*)&row[32 + kg * 8];
        float4 g1 = *(const float4*)&row[32 + kg * 8 + 4];
        ma[n][1] = pack_bf8(g0, g1);
    }

    // ---- out phase: 8 passes x 128 b-rows, barrier-free, float4 stores ----
#pragma unroll 1
    for (int p = 0; p < 8; ++p) {
#pragma unroll
        for (int mt = 0; mt < 2; ++mt) {
            const int b = p * 128 + w * 32 + mt * 16 + m;
            short8 xb0 = *(const short8*)&x0b[(size_t)b * 64 + kg * 8];        // k 0..31
            short8 xb1 = *(const short8*)&x0b[(size_t)b * 64 + 32 + kg * 8];   // k 32..63
            float* outb = out + (size_t)b * 64000 + (size_t)t * 64;
#pragma unroll
            for (int n = 0; n < 4; ++n) {
                floatx4 acc = {0.f, 0.f, 0.f, 0.f};
                acc = __builtin_amdgcn_mfma_f32_16x16x32_bf16(ma[n][0], xb0, acc, 0, 0, 0);
                acc = __builtin_amdgcn_mfma_f32_16x16x32_bf16(ma[n][1], xb1, acc, 0, 0, 0);
                // D (swapped operands): col = lane&15 = b_local, row = kg*4 + v = i_local
                // -> acc = y[b][t][n*16 + kg*4 .. +4): one aligned float4 store
                *(floatx4*)&outb[n * 16 + kg * 4] = acc;
            }
        }
    }
}

extern "C" void kernel_launch(void* const* d_in, const int* in_sizes, int n_in,
                              void* d_out, int out_size, void* d_ws, size_t ws_size,
                              hipStream_t stream)
{
    const float* inp = (const float*)d_in[0];   // (1024, 1000, 64) fp32
    const float* K   = (const float*)d_in[1];   // (64, 64) fp32
    float* out = (float*)d_out;                 // (1024, 1000, 64) fp32
    float* ws  = (float*)d_ws;                  // uses [8.19 MB, 8.49 MB) only

    // 1) expm + power-of-two seeds (block 0) and x0 bf16 conversion (blocks 1..16)
    hipLaunchKernelGGL(k_build, dim3(17), dim3(256), 0, stream, K, inp, ws);
    // 2) fused: per-t power chain + output GEMM, one block per timestep
    hipLaunchKernelGGL(k_fused, dim3(NMAT), dim3(256), 0, stream, ws, out);
}